// Round 1
// baseline (17529.193 us; speedup 1.0000x reference)
//
#include <hip/hip_runtime.h>
#include <hip/hip_bf16.h>

// Problem dims
#define Bx  128
#define Tt  1024
#define INx 256
#define Hx  512
#define G4  2048   // 4*H
#define FCx 64

typedef _Float16 half8 __attribute__((ext_vector_type(8)));
typedef float float4v __attribute__((ext_vector_type(4)));

__device__ __forceinline__ float sigf(float x) { return 1.0f / (1.0f + expf(-x)); }

__device__ __forceinline__ half8 cvt_a(const float* __restrict__ p) {
    float4v f0 = *(const float4v*)(p);
    float4v f1 = *(const float4v*)(p + 4);
    half8 a;
    a[0] = (_Float16)f0[0]; a[1] = (_Float16)f0[1];
    a[2] = (_Float16)f0[2]; a[3] = (_Float16)f0[3];
    a[4] = (_Float16)f1[0]; a[5] = (_Float16)f1[1];
    a[6] = (_Float16)f1[2]; a[7] = (_Float16)f1[3];
    return a;
}

// fp32 -> fp16 weight conversion
__global__ void k_cvt(const float* __restrict__ s, _Float16* __restrict__ d, int n) {
    int i = blockIdx.x * blockDim.x + threadIdx.x;
    int st = gridDim.x * blockDim.x;
    for (; i < n; i += st) d[i] = (_Float16)s[i];
}

__global__ void k_bias(const float* __restrict__ a, const float* __restrict__ b,
                       float* __restrict__ d, int n) {
    int i = blockIdx.x * blockDim.x + threadIdx.x;
    int st = gridDim.x * blockDim.x;
    for (; i < n; i += st) d[i] = a[i] + b[i];
}

__global__ void k_zero(float* __restrict__ d, int n) {
    int i = blockIdx.x * blockDim.x + threadIdx.x;
    int st = gridDim.x * blockDim.x;
    for (; i < n; i += st) d[i] = 0.0f;
}

// One pipeline iteration: layer0 computes step t, layer1 computes step t-1.
// Grid: 512 blocks x 256 threads.
//   blk&1      -> layer L
//   (blk>>1)&31 -> unit group ug (16 hidden units each)
//   (blk>>1)>>5 -> batch group bg (16 batch rows each)
// Each wave (4 per block) computes one gate's 16x16 output tile via MFMA.
__global__ __launch_bounds__(256) void lstm_step(
    int t, const float* __restrict__ x,
    const _Float16* __restrict__ Wih0, const _Float16* __restrict__ Whh0,
    const _Float16* __restrict__ Wih1, const _Float16* __restrict__ Whh1,
    const float* __restrict__ bias0, const float* __restrict__ bias1,
    float* __restrict__ c0, float* __restrict__ c1,
    _Float16* __restrict__ buf0, _Float16* __restrict__ buf1)
{
    const int blk = blockIdx.x;
    const int L = blk & 1;
    if (L == 0 && t >= Tt) return;   // layer0 done on last iteration
    if (L == 1 && t == 0) return;    // layer1 idle on first iteration
    const int rest = blk >> 1;
    const int ug = rest & 31;
    const int bg = rest >> 5;
    const int s = L ? (t - 1) : t;

    const int tid  = threadIdx.x;
    const int g    = tid >> 6;   // gate index: 0=i 1=f 2=g 3=o
    const int lane = tid & 63;
    const int n    = lane & 15;  // A-row (batch-in-tile) AND B-col (unit-in-tile)
    const int quad = lane >> 4;  // k = k0 + quad*8 + j

    float4v acc = {0.f, 0.f, 0.f, 0.f};

    const int mrow = bg * 16 + n;                 // global batch row for A-frag
    const int wrow = g * Hx + ug * 16 + n;        // global gate row for B-frag
    const int kq = quad * 8;

    if (L == 0) {
        // phase 1: x_t @ Wih0^T  (K = 256, fp32 source converted on the fly)
        const float* arow = x + ((size_t)mrow * Tt + s) * INx;
        const _Float16* brow = Wih0 + (size_t)wrow * INx;
        #pragma unroll 4
        for (int k0 = 0; k0 < INx; k0 += 32) {
            half8 a = cvt_a(arow + k0 + kq);
            half8 b = *(const half8*)(brow + k0 + kq);
            acc = __builtin_amdgcn_mfma_f32_16x16x32_f16(a, b, acc, 0, 0, 0);
        }
        // phase 2: h0_{s-1} @ Whh0^T  (K = 512, fp16 source)
        const _Float16* ah = buf0 + ((s & 1) ^ 1) * (Bx * Hx) + (size_t)mrow * Hx;
        const _Float16* bh = Whh0 + (size_t)wrow * Hx;
        #pragma unroll 4
        for (int k0 = 0; k0 < Hx; k0 += 32) {
            half8 a = *(const half8*)(ah + k0 + kq);
            half8 b = *(const half8*)(bh + k0 + kq);
            acc = __builtin_amdgcn_mfma_f32_16x16x32_f16(a, b, acc, 0, 0, 0);
        }
    } else {
        // phase 1: h0_s @ Wih1^T  (K = 512)
        const _Float16* ax = buf0 + (s & 1) * (Bx * Hx) + (size_t)mrow * Hx;
        const _Float16* bxw = Wih1 + (size_t)wrow * Hx;
        #pragma unroll 4
        for (int k0 = 0; k0 < Hx; k0 += 32) {
            half8 a = *(const half8*)(ax + k0 + kq);
            half8 b = *(const half8*)(bxw + k0 + kq);
            acc = __builtin_amdgcn_mfma_f32_16x16x32_f16(a, b, acc, 0, 0, 0);
        }
        // phase 2: h1_{s-1} @ Whh1^T  (K = 512)
        const _Float16* ah = buf1 + ((s & 1) ^ 1) * (Bx * Hx) + (size_t)mrow * Hx;
        const _Float16* bh = Whh1 + (size_t)wrow * Hx;
        #pragma unroll 4
        for (int k0 = 0; k0 < Hx; k0 += 32) {
            half8 a = *(const half8*)(ah + k0 + kq);
            half8 b = *(const half8*)(bh + k0 + kq);
            acc = __builtin_amdgcn_mfma_f32_16x16x32_f16(a, b, acc, 0, 0, 0);
        }
    }

    // bias depends on gate row (C/D col = lane&15 = n)
    const float* biasL = L ? bias1 : bias0;
    const float bv = biasL[wrow];

    // C/D layout: col = lane&15 (unit), row = quad*4 + r (batch)
    __shared__ float gbuf[4][16][17];
    #pragma unroll
    for (int r = 0; r < 4; ++r)
        gbuf[g][quad * 4 + r][n] = acc[r] + bv;
    __syncthreads();

    // elementwise LSTM cell update: 256 threads = 16 batch x 16 units
    const int m = tid >> 4;
    const int u = tid & 15;
    const float iv = gbuf[0][m][u];
    const float fv = gbuf[1][m][u];
    const float gv = gbuf[2][m][u];
    const float ov = gbuf[3][m][u];
    const int b = bg * 16 + m;
    const int uu = ug * 16 + u;
    float* cL = L ? c1 : c0;
    const size_t cidx = (size_t)b * Hx + uu;
    const float cold = cL[cidx];
    const float cn = sigf(fv) * cold + sigf(iv) * tanhf(gv);
    const float hn = sigf(ov) * tanhf(cn);
    cL[cidx] = cn;
    _Float16* hb = (L ? buf1 : buf0) + (s & 1) * (Bx * Hx);
    hb[cidx] = (_Float16)hn;
}

// FC head: z = relu(h1_last @ fc_w^T + fc_b); out = sigmoid(z @ fc2_w^T + fc2_b)
__global__ __launch_bounds__(64) void fc_kernel(
    const _Float16* __restrict__ h1,   // final h1, parity-1 buffer
    const float* __restrict__ fc_w, const float* __restrict__ fc_b,
    const float* __restrict__ fc2_w, const float* __restrict__ fc2_b,
    float* __restrict__ out)
{
    const int b = blockIdx.x;
    const int j = threadIdx.x;
    const _Float16* h = h1 + (size_t)b * Hx;
    const float* w = fc_w + (size_t)j * Hx;
    float acc = fc_b[j];
    for (int k = 0; k < Hx; ++k) acc += (float)h[k] * w[k];
    float p = fmaxf(acc, 0.0f) * fc2_w[j];
    #pragma unroll
    for (int off = 32; off; off >>= 1) p += __shfl_down(p, off);
    if (j == 0) out[b] = 1.0f / (1.0f + expf(-(p + fc2_b[0])));
}

extern "C" void kernel_launch(void* const* d_in, const int* in_sizes, int n_in,
                              void* d_out, int out_size, void* d_ws, size_t ws_size,
                              hipStream_t stream) {
    const float* x       = (const float*)d_in[0];
    // d_in[1] = length_list : unused by the reference output
    const float* w_ih_l0 = (const float*)d_in[2];
    const float* w_hh_l0 = (const float*)d_in[3];
    const float* b_ih_l0 = (const float*)d_in[4];
    const float* b_hh_l0 = (const float*)d_in[5];
    const float* w_ih_l1 = (const float*)d_in[6];
    const float* w_hh_l1 = (const float*)d_in[7];
    const float* b_ih_l1 = (const float*)d_in[8];
    const float* b_hh_l1 = (const float*)d_in[9];
    const float* fc_w    = (const float*)d_in[10];
    const float* fc_b    = (const float*)d_in[11];
    const float* fc2_w   = (const float*)d_in[12];
    const float* fc2_b   = (const float*)d_in[13];
    float* out = (float*)d_out;

    // workspace layout (bytes)
    char* ws = (char*)d_ws;
    _Float16* Wih0 = (_Float16*)(ws);                    // 2048*256*2 = 1,048,576
    _Float16* Whh0 = (_Float16*)(ws + 1048576);          // 2048*512*2 = 2,097,152
    _Float16* Wih1 = (_Float16*)(ws + 3145728);          // 2,097,152
    _Float16* Whh1 = (_Float16*)(ws + 5242880);          // 2,097,152
    float*    bias0 = (float*)(ws + 7340032);            // 8,192
    float*    bias1 = (float*)(ws + 7348224);            // 8,192
    float*    c0    = (float*)(ws + 7356416);            // 262,144
    float*    c1    = (float*)(ws + 7618560);            // 262,144
    _Float16* buf0  = (_Float16*)(ws + 7880704);         // 2 x 128*512 f16 = 262,144
    _Float16* buf1  = (_Float16*)(ws + 8142848);         // 262,144
    // total ~8.02 MB

    // prologue: convert weights to fp16, fold biases, zero states (c0,c1,buf0,buf1 contiguous)
    k_cvt<<<512, 256, 0, stream>>>(w_ih_l0, Wih0, G4 * INx);
    k_cvt<<<512, 256, 0, stream>>>(w_hh_l0, Whh0, G4 * Hx);
    k_cvt<<<512, 256, 0, stream>>>(w_ih_l1, Wih1, G4 * Hx);
    k_cvt<<<512, 256, 0, stream>>>(w_hh_l1, Whh1, G4 * Hx);
    k_bias<<<8, 256, 0, stream>>>(b_ih_l0, b_hh_l0, bias0, G4);
    k_bias<<<8, 256, 0, stream>>>(b_ih_l1, b_hh_l1, bias1, G4);
    k_zero<<<256, 256, 0, stream>>>(c0, 262144);  // zeroes c0,c1,buf0,buf1 (1 MB)

    // pipelined recurrence: iteration t = layer0 step t + layer1 step t-1
    for (int t = 0; t <= Tt; ++t)
        lstm_step<<<512, 256, 0, stream>>>(t, x, Wih0, Whh0, Wih1, Whh1,
                                           bias0, bias1, c0, c1, buf0, buf1);

    // final h1 is at parity (1023 & 1) = 1
    fc_kernel<<<Bx, 64, 0, stream>>>(buf1 + Bx * Hx, fc_w, fc_b, fc2_w, fc2_b, out);
}

// Round 2
// 14977.654 us; speedup vs baseline: 1.1704x; 1.1704x over previous
//
#include <hip/hip_runtime.h>
#include <hip/hip_bf16.h>

// Problem dims
#define Bx  128
#define Tt  1024
#define INx 256
#define Hx  512
#define G4  2048
#define FCx 64

#define NGROUP 4
#define RB     32          // batch rows per group
#define BLKS_PER_GROUP 64  // 2 layers x 32 unit-groups
#define LDS_STRIDE 264     // 256 fp16 + 8 pad  (132 dwords == 4 mod 32 -> uniform banks)

typedef _Float16 half8 __attribute__((ext_vector_type(8)));
typedef float float4v __attribute__((ext_vector_type(4)));

__device__ __forceinline__ float sigf(float x) { return 1.0f / (1.0f + expf(-x)); }

__device__ __forceinline__ half8 cvt8(const float* __restrict__ p) {
    float4v f0 = *(const float4v*)(p);
    float4v f1 = *(const float4v*)(p + 4);
    half8 a;
    a[0] = (_Float16)f0[0]; a[1] = (_Float16)f0[1];
    a[2] = (_Float16)f0[2]; a[3] = (_Float16)f0[3];
    a[4] = (_Float16)f1[0]; a[5] = (_Float16)f1[1];
    a[6] = (_Float16)f1[2]; a[7] = (_Float16)f1[3];
    return a;
}

// 8 MFMA chunks (K=256) from an LDS half-buffer against register B-frags [C0..C0+7]
template<int C0>
__device__ __forceinline__ void mfma8(const _Float16* buf, const half8 (&Bf)[16],
                                      int arow, int koff, float4v& acc) {
    #pragma unroll
    for (int c = 0; c < 8; ++c) {
        half8 a = *(const half8*)(buf + arow + c * 32 + koff);
        acc = __builtin_amdgcn_mfma_f32_16x16x32_f16(a, Bf[C0 + c], acc, 0, 0, 0);
    }
}

__global__ void zero_ctr(unsigned int* __restrict__ p) {
    p[threadIdx.x] = 0u;   // 256 uints = 1 KB counter region
}

// Persistent LSTM kernel: 256 blocks x 512 threads, 1 block/CU (all co-resident).
// Block mapping: xcd=blk&7, group g=xcd>>1 (64 blocks/group on an XCD pair),
// id=((blk>>3)<<1)|(xcd&1): L=id&1 (layer), ug=id>>1 (16-unit group).
// Each wave (8/block) pins B-fragments of its gate's weight rows in VGPRs:
//   Bp1 = input-side weights (Wih: K=256 for L0, K=512 for L1), Bp2 = Whh (K=512).
// Per virtual step t: L0 computes h0[t], L1 computes h1[t-1] (software pipeline,
// one group barrier per step). c-state lives in one VGPR per thread.
__global__ __launch_bounds__(512, 2) void lstm_persist(
    const float* __restrict__ x,
    const float* __restrict__ w_ih_l0, const float* __restrict__ w_hh_l0,
    const float* __restrict__ b_ih_l0, const float* __restrict__ b_hh_l0,
    const float* __restrict__ w_ih_l1, const float* __restrict__ w_hh_l1,
    const float* __restrict__ b_ih_l1, const float* __restrict__ b_hh_l1,
    unsigned int* __restrict__ ctr,
    _Float16* __restrict__ h0buf, _Float16* __restrict__ h1buf)
{
    __shared__ _Float16 bufA[32 * LDS_STRIDE];   // 16.5 KB
    __shared__ _Float16 bufB[32 * LDS_STRIDE];   // 16.5 KB
    __shared__ float gbuf[4][32][17];            // 8.5 KB  (total ~41.5 KB LDS)

    const int blk  = blockIdx.x;
    const int xcd  = blk & 7;
    const int g    = xcd >> 1;
    const int id   = ((blk >> 3) << 1) | (xcd & 1);
    const int L    = id & 1;
    const int ug   = id >> 1;

    const int tid  = threadIdx.x;
    const int lane = tid & 63;
    const int wv   = tid >> 6;
    const int n    = lane & 15;     // MFMA: A-row (batch) / B-col (unit) / C-col
    const int quad = lane >> 4;
    const int gt   = wv & 3;        // gate 0..3
    const int bh   = wv >> 2;       // batch half 0..1
    const int arow = (bh * 16 + n) * LDS_STRIDE;
    const int koff = quad * 8;

    const int ur = tid >> 4;        // staging/update: row 0..31
    const int uu = tid & 15;        // staging/update: unit 0..15

    const int wrow = gt * Hx + ug * 16 + n;   // weight row this lane feeds

    // ---- startup: pin weight B-fragments in registers (one-time) ----
    half8 Bp1[16], Bp2[16];
    {
        const float* Wi = L ? w_ih_l1 : w_ih_l0;
        const float* Wh = L ? w_hh_l1 : w_hh_l0;
        const int KI = L ? Hx : INx;
        #pragma unroll
        for (int c = 0; c < 16; ++c) {
            half8 v = {};
            if (c * 32 < KI) v = cvt8(Wi + (size_t)wrow * KI + c * 32 + koff);
            Bp1[c] = v;
        }
        #pragma unroll
        for (int c = 0; c < 16; ++c)
            Bp2[c] = cvt8(Wh + (size_t)wrow * Hx + c * 32 + koff);
    }
    float bias_g[4];
    {
        const float* bi  = L ? b_ih_l1 : b_ih_l0;
        const float* bhh = L ? b_hh_l1 : b_hh_l0;
        #pragma unroll
        for (int q = 0; q < 4; ++q) {
            int row = q * Hx + ug * 16 + uu;
            bias_g[q] = bi[row] + bhh[row];
        }
    }
    float cst = 0.0f;                               // cell state for (g*32+ur, ug*16+uu)
    unsigned int* myctr = ctr + g * 64;             // 256-B spaced counters
    const size_t grow = (size_t)(g * RB);
    const float* xbase = x + grow * Tt * INx;

    for (int t = 0; t <= Tt; ++t) {
        // ---- release previous step's h writes + arrive ----
        __syncthreads();
        if (tid == 0) { __threadfence(); atomicAdd(myctr, 1u); }

        const int s = L ? (t - 1) : t;
        const bool active = L ? (t >= 1) : (t < Tt);
        float4v acc = {0.f, 0.f, 0.f, 0.f};

        // ---- pre-spin: L0's x-phase is barrier-independent ----
        if (!L && active) {
            const float* xp = xbase + (size_t)ur * (Tt * (size_t)INx) + (size_t)s * INx;
            #pragma unroll
            for (int i = 0; i < 2; ++i) {
                int col8 = (uu + 16 * i) * 8;
                float4v f0 = *(const float4v*)(xp + col8);
                float4v f1 = *(const float4v*)(xp + col8 + 4);
                half8 hv;
                hv[0]=(_Float16)f0[0]; hv[1]=(_Float16)f0[1]; hv[2]=(_Float16)f0[2]; hv[3]=(_Float16)f0[3];
                hv[4]=(_Float16)f1[0]; hv[5]=(_Float16)f1[1]; hv[6]=(_Float16)f1[2]; hv[7]=(_Float16)f1[3];
                *(half8*)(bufA + ur * LDS_STRIDE + col8) = hv;
            }
            __syncthreads();
            mfma8<0>(bufA, Bp1, arow, koff, acc);   // x @ Wih0^T
        }

        // ---- spin until all 64 group blocks arrived at step t ----
        if (tid == 0) {
            const unsigned target = (unsigned)(t + 1) * 64u;
            while (__hip_atomic_load(myctr, __ATOMIC_RELAXED, __HIP_MEMORY_SCOPE_AGENT) < target)
                __builtin_amdgcn_s_sleep(1);
            __threadfence();                         // acquire
        }
        __syncthreads();

        // ---- post-spin: recurrent phases (double-buffered staging) ----
        if (active) {
            if (!L) {
                if (s > 0) {   // h0[s-1] @ Whh0^T
                    const _Float16* hp = h0buf + (size_t)((s - 1) & 1) * (Bx * Hx) + (grow + ur) * Hx;
                    half8 r0 = *(const half8*)(hp + uu * 8);
                    half8 r1 = *(const half8*)(hp + (uu + 16) * 8);
                    half8 r2 = *(const half8*)(hp + 256 + uu * 8);
                    half8 r3 = *(const half8*)(hp + 256 + (uu + 16) * 8);
                    *(half8*)(bufB + ur * LDS_STRIDE + uu * 8)        = r0;
                    *(half8*)(bufB + ur * LDS_STRIDE + (uu + 16) * 8) = r1;
                    __syncthreads();
                    *(half8*)(bufA + ur * LDS_STRIDE + uu * 8)        = r2;
                    *(half8*)(bufA + ur * LDS_STRIDE + (uu + 16) * 8) = r3;
                    mfma8<0>(bufB, Bp2, arow, koff, acc);
                    __syncthreads();
                    mfma8<8>(bufA, Bp2, arow, koff, acc);
                }
            } else {
                // phase1: h0[s] @ Wih1^T
                const _Float16* hp0 = h0buf + (size_t)(s & 1) * (Bx * Hx) + (grow + ur) * Hx;
                half8 q0 = *(const half8*)(hp0 + uu * 8);
                half8 q1 = *(const half8*)(hp0 + (uu + 16) * 8);
                half8 q2 = *(const half8*)(hp0 + 256 + uu * 8);
                half8 q3 = *(const half8*)(hp0 + 256 + (uu + 16) * 8);
                *(half8*)(bufA + ur * LDS_STRIDE + uu * 8)        = q0;
                *(half8*)(bufA + ur * LDS_STRIDE + (uu + 16) * 8) = q1;
                __syncthreads();
                if (s > 0) {
                    // phase2 loads issued early, overlap phase1 MFMAs
                    const _Float16* hp1 = h1buf + (size_t)((s - 1) & 1) * (Bx * Hx) + (grow + ur) * Hx;
                    half8 p0 = *(const half8*)(hp1 + uu * 8);
                    half8 p1 = *(const half8*)(hp1 + (uu + 16) * 8);
                    half8 p2 = *(const half8*)(hp1 + 256 + uu * 8);
                    half8 p3 = *(const half8*)(hp1 + 256 + (uu + 16) * 8);
                    *(half8*)(bufB + ur * LDS_STRIDE + uu * 8)        = q2;
                    *(half8*)(bufB + ur * LDS_STRIDE + (uu + 16) * 8) = q3;
                    mfma8<0>(bufA, Bp1, arow, koff, acc);
                    __syncthreads();
                    *(half8*)(bufA + ur * LDS_STRIDE + uu * 8)        = p0;
                    *(half8*)(bufA + ur * LDS_STRIDE + (uu + 16) * 8) = p1;
                    mfma8<8>(bufB, Bp1, arow, koff, acc);
                    __syncthreads();
                    *(half8*)(bufB + ur * LDS_STRIDE + uu * 8)        = p2;
                    *(half8*)(bufB + ur * LDS_STRIDE + (uu + 16) * 8) = p3;
                    mfma8<0>(bufA, Bp2, arow, koff, acc);   // h1[s-1] @ Whh1^T
                    __syncthreads();
                    mfma8<8>(bufB, Bp2, arow, koff, acc);
                } else {
                    *(half8*)(bufB + ur * LDS_STRIDE + uu * 8)        = q2;
                    *(half8*)(bufB + ur * LDS_STRIDE + (uu + 16) * 8) = q3;
                    mfma8<0>(bufA, Bp1, arow, koff, acc);
                    __syncthreads();
                    mfma8<8>(bufB, Bp1, arow, koff, acc);
                }
            }

            // ---- gate exchange + cell update ----
            #pragma unroll
            for (int r = 0; r < 4; ++r)
                gbuf[gt][bh * 16 + quad * 4 + r][n] = acc[r];   // C/D: col=lane&15, row=quad*4+r
            __syncthreads();
            float iv = gbuf[0][ur][uu] + bias_g[0];
            float fv = gbuf[1][ur][uu] + bias_g[1];
            float gv = gbuf[2][ur][uu] + bias_g[2];
            float ov = gbuf[3][ur][uu] + bias_g[3];
            float cn = sigf(fv) * cst + sigf(iv) * tanhf(gv);
            float hn = sigf(ov) * tanhf(cn);
            cst = cn;
            _Float16* hd = (L ? h1buf : h0buf) + (size_t)(s & 1) * (Bx * Hx)
                         + (grow + ur) * Hx + ug * 16 + uu;
            *hd = (_Float16)hn;
        }
    }
}

// FC head: z = relu(h1_last @ fc_w^T + fc_b); out = sigmoid(z @ fc2_w^T + fc2_b)
__global__ __launch_bounds__(64) void fc_kernel(
    const _Float16* __restrict__ h1,
    const float* __restrict__ fc_w, const float* __restrict__ fc_b,
    const float* __restrict__ fc2_w, const float* __restrict__ fc2_b,
    float* __restrict__ out)
{
    const int b = blockIdx.x;
    const int j = threadIdx.x;
    const _Float16* h = h1 + (size_t)b * Hx;
    const float* w = fc_w + (size_t)j * Hx;
    float acc = fc_b[j];
    for (int k = 0; k < Hx; ++k) acc += (float)h[k] * w[k];
    float p = fmaxf(acc, 0.0f) * fc2_w[j];
    #pragma unroll
    for (int off = 32; off; off >>= 1) p += __shfl_down(p, off);
    if (j == 0) out[b] = 1.0f / (1.0f + expf(-(p + fc2_b[0])));
}

extern "C" void kernel_launch(void* const* d_in, const int* in_sizes, int n_in,
                              void* d_out, int out_size, void* d_ws, size_t ws_size,
                              hipStream_t stream) {
    const float* x       = (const float*)d_in[0];
    // d_in[1] = length_list : unused by the reference output
    const float* w_ih_l0 = (const float*)d_in[2];
    const float* w_hh_l0 = (const float*)d_in[3];
    const float* b_ih_l0 = (const float*)d_in[4];
    const float* b_hh_l0 = (const float*)d_in[5];
    const float* w_ih_l1 = (const float*)d_in[6];
    const float* w_hh_l1 = (const float*)d_in[7];
    const float* b_ih_l1 = (const float*)d_in[8];
    const float* b_hh_l1 = (const float*)d_in[9];
    const float* fc_w    = (const float*)d_in[10];
    const float* fc_b    = (const float*)d_in[11];
    const float* fc2_w   = (const float*)d_in[12];
    const float* fc2_b   = (const float*)d_in[13];
    float* out = (float*)d_out;

    // workspace: [0,1KB) barrier counters | [4KB, +256KB) h0 ring | next 256KB h1 ring
    char* ws = (char*)d_ws;
    unsigned int* ctr = (unsigned int*)ws;
    _Float16* h0buf = (_Float16*)(ws + 4096);
    _Float16* h1buf = (_Float16*)(ws + 4096 + 2 * Bx * Hx * sizeof(_Float16));

    zero_ctr<<<1, 256, 0, stream>>>(ctr);
    lstm_persist<<<256, 512, 0, stream>>>(x,
        w_ih_l0, w_hh_l0, b_ih_l0, b_hh_l0,
        w_ih_l1, w_hh_l1, b_ih_l1, b_hh_l1,
        ctr, h0buf, h1buf);
    // final h1 is at ring parity (1023 & 1) = 1
    fc_kernel<<<Bx, 64, 0, stream>>>(h1buf + Bx * Hx, fc_w, fc_b, fc2_w, fc2_b, out);
}

// Round 3
// 4698.420 us; speedup vs baseline: 3.7309x; 3.1878x over previous
//
#include <hip/hip_runtime.h>
#include <hip/hip_bf16.h>
#include <stdint.h>

// Problem dims
#define Bx  128
#define Tt  1024
#define INx 256
#define Hx  512
#define NG  8            // batch groups
#define RB  16           // batch rows per group
#define RING 8           // h0/h1 ring slots
#define LSTR 520         // LDS A-row stride in fp16 (512 + 8 pad)
#define RSLOT (Bx*Hx)    // ring slot elements (fp16)

typedef _Float16 half8 __attribute__((ext_vector_type(8)));
typedef float float4v __attribute__((ext_vector_type(4)));

__device__ __forceinline__ float sigf(float x) { return 1.0f / (1.0f + expf(-x)); }

__device__ __forceinline__ half8 cvt8(const float* __restrict__ p) {
    float4v f0 = *(const float4v*)(p);
    float4v f1 = *(const float4v*)(p + 4);
    half8 a;
    a[0] = (_Float16)f0[0]; a[1] = (_Float16)f0[1];
    a[2] = (_Float16)f0[2]; a[3] = (_Float16)f0[3];
    a[4] = (_Float16)f1[0]; a[5] = (_Float16)f1[1];
    a[6] = (_Float16)f1[2]; a[7] = (_Float16)f1[3];
    return a;
}

// MALL-coherent (cross-XCD) 16B load / 4B store: sc0 sc1 bypass L1/L2.
__device__ __forceinline__ half8 ldcc(const _Float16* p) {
    half8 v;
    asm volatile("global_load_dwordx4 %0, %1, off sc0 sc1" : "=v"(v) : "v"(p) : "memory");
    return v;
}
__device__ __forceinline__ void stcc(_Float16* p, unsigned v) {
    asm volatile("global_store_dword %0, %1, off sc0 sc1" :: "v"(p), "v"(v) : "memory");
}
__device__ __forceinline__ void vm0() { asm volatile("s_waitcnt vmcnt(0)" ::: "memory"); }
__device__ __forceinline__ unsigned ldctr(const unsigned* p) {
    return __hip_atomic_load(p, __ATOMIC_RELAXED, __HIP_MEMORY_SCOPE_AGENT);
}

// A-read once, two MFMAs (2 unit-tiles) per K-chunk.
template<int NC, int NA>
__device__ __forceinline__ void mfma2(const _Float16* buf, int arow, int koff,
                                      const half8 (&B0)[NA], const half8 (&B1)[NA],
                                      float4v& a0, float4v& a1) {
    #pragma unroll
    for (int c = 0; c < NC; ++c) {
        half8 a = *(const half8*)(buf + arow + c * 32 + koff);
        a0 = __builtin_amdgcn_mfma_f32_16x16x32_f16(a, B0[c], a0, 0, 0, 0);
        a1 = __builtin_amdgcn_mfma_f32_16x16x32_f16(a, B1[c], a1, 0, 0, 0);
    }
}

__global__ void zero_ctr(unsigned* __restrict__ p) {
    __hip_atomic_store(&p[threadIdx.x], 0u, __ATOMIC_RELAXED, __HIP_MEMORY_SCOPE_AGENT);
}

// Persistent LSTM: 256 blocks x 256 threads (4 waves), 1 block/CU.
// blk>>5 = group g (16 batch rows); (blk&31): L=id&1, ub=id>>1 (32 units).
// Wave w = gate w; each wave computes two 16x16 unit-tiles with B-frags pinned
// in VGPRs (K<=512 per operand matrix, 256 VGPRs of weights).
// Sync: per-group per-layer arrival counters at MALL; h via sc0sc1 ring buffers.
__global__ __launch_bounds__(256, 1) void lstm_persist(
    const float* __restrict__ x,
    const float* __restrict__ w_ih_l0, const float* __restrict__ w_hh_l0,
    const float* __restrict__ b_ih_l0, const float* __restrict__ b_hh_l0,
    const float* __restrict__ w_ih_l1, const float* __restrict__ w_hh_l1,
    const float* __restrict__ b_ih_l1, const float* __restrict__ b_hh_l1,
    unsigned* __restrict__ ctr,
    _Float16* __restrict__ h0r, _Float16* __restrict__ h1r)
{
    __shared__ _Float16 bufX[RB * LSTR];   // 16.6 KB
    __shared__ _Float16 bufH[RB * LSTR];   // 16.6 KB
    __shared__ float gbuf[4][RB][33];      // 8.4 KB

    const int blk = blockIdx.x;
    const int g   = blk >> 5;
    const int id  = blk & 31;
    const int L   = id & 1;
    const int ub  = id >> 1;
    const int u0  = ub * 32;
    const int grow = g * RB;

    const int tid  = threadIdx.x;
    const int wv   = tid >> 6;      // gate
    const int lane = tid & 63;
    const int n    = lane & 15;
    const int quad = lane >> 4;
    const int koff = quad * 8;
    const int arow = n * LSTR;
    const int srow = tid >> 4;      // staging/update row 0..15
    const int sc   = tid & 15;      // staging col / update unit-pair

    unsigned* c0p = ctr + g * 64;
    unsigned* c1p = ctr + g * 64 + 32;

    // biases for this thread's 2 update units, all 4 gates
    const float* bi = L ? b_ih_l1 : b_ih_l0;
    const float* bh = L ? b_hh_l1 : b_hh_l0;
    float bias[4][2];
    #pragma unroll
    for (int q = 0; q < 4; ++q)
        #pragma unroll
        for (int j = 0; j < 2; ++j) {
            int u = q * Hx + u0 + 2 * sc + j;
            bias[q][j] = bi[u] + bh[u];
        }

    float cs0 = 0.0f, cs1 = 0.0f;   // cell states for the 2 update units

    if (L == 0) {
        // -------- layer 0 --------
        half8 W1a[8], W1b[8], W2a[16], W2b[16];
        const int wrA = wv * Hx + u0 + n, wrB = wrA + 16;
        #pragma unroll
        for (int c = 0; c < 8; ++c) {
            W1a[c] = cvt8(w_ih_l0 + (size_t)wrA * INx + c * 32 + koff);
            W1b[c] = cvt8(w_ih_l0 + (size_t)wrB * INx + c * 32 + koff);
        }
        #pragma unroll
        for (int c = 0; c < 16; ++c) {
            W2a[c] = cvt8(w_hh_l0 + (size_t)wrA * Hx + c * 32 + koff);
            W2b[c] = cvt8(w_hh_l0 + (size_t)wrB * Hx + c * 32 + koff);
        }

        for (int s = 0; s < Tt; ++s) {
            // stage x_s (cached loads; overlaps the spin below)
            const float* xp = x + ((size_t)(grow + srow) * Tt + s) * INx + sc * 16;
            {
                float4v f0 = *(const float4v*)(xp);
                float4v f1 = *(const float4v*)(xp + 4);
                float4v f2 = *(const float4v*)(xp + 8);
                float4v f3 = *(const float4v*)(xp + 12);
                half8 hA, hB;
                hA[0]=(_Float16)f0[0]; hA[1]=(_Float16)f0[1]; hA[2]=(_Float16)f0[2]; hA[3]=(_Float16)f0[3];
                hA[4]=(_Float16)f1[0]; hA[5]=(_Float16)f1[1]; hA[6]=(_Float16)f1[2]; hA[7]=(_Float16)f1[3];
                hB[0]=(_Float16)f2[0]; hB[1]=(_Float16)f2[1]; hB[2]=(_Float16)f2[2]; hB[3]=(_Float16)f2[3];
                hB[4]=(_Float16)f3[0]; hB[5]=(_Float16)f3[1]; hB[6]=(_Float16)f3[2]; hB[7]=(_Float16)f3[3];
                *(half8*)(bufX + srow * LSTR + sc * 16)     = hA;
                *(half8*)(bufX + srow * LSTR + sc * 16 + 8) = hB;
            }
            // spin: own-layer barrier; ring-guard on L1 every 4 steps
            if (tid == 0 && s > 0) {
                unsigned t0 = 16u * (unsigned)s;
                unsigned t1 = (((s & 3) == 0) && s >= 8) ? 16u * (unsigned)(s - 4) : 0u;
                unsigned a = ldctr(c0p);
                unsigned b = t1 ? ldctr(c1p) : 0u;
                while (a < t0 || b < t1) {
                    __builtin_amdgcn_s_sleep(1);
                    a = ldctr(c0p);
                    if (t1) b = ldctr(c1p);
                }
            }
            __syncthreads();
            float4v a0 = {0.f,0.f,0.f,0.f}, a1 = {0.f,0.f,0.f,0.f};
            mfma2<8>(bufX, arow, koff, W1a, W1b, a0, a1);
            if (s > 0) {
                const _Float16* hp = h0r + (size_t)((s - 1) & 7) * RSLOT
                                   + (size_t)(grow + srow) * Hx + sc * 32;
                half8 v0 = ldcc(hp), v1 = ldcc(hp + 8), v2 = ldcc(hp + 16), v3 = ldcc(hp + 24);
                vm0();
                *(half8*)(bufH + srow * LSTR + sc * 32)      = v0;
                *(half8*)(bufH + srow * LSTR + sc * 32 + 8)  = v1;
                *(half8*)(bufH + srow * LSTR + sc * 32 + 16) = v2;
                *(half8*)(bufH + srow * LSTR + sc * 32 + 24) = v3;
                __syncthreads();
                mfma2<16>(bufH, arow, koff, W2a, W2b, a0, a1);
            }
            #pragma unroll
            for (int r = 0; r < 4; ++r) {
                gbuf[wv][quad * 4 + r][n]      = a0[r];
                gbuf[wv][quad * 4 + r][16 + n] = a1[r];
            }
            __syncthreads();
            {
                unsigned pv = 0;
                #pragma unroll
                for (int j = 0; j < 2; ++j) {
                    float iv = gbuf[0][srow][2 * sc + j] + bias[0][j];
                    float fv = gbuf[1][srow][2 * sc + j] + bias[1][j];
                    float gv = gbuf[2][srow][2 * sc + j] + bias[2][j];
                    float ov = gbuf[3][srow][2 * sc + j] + bias[3][j];
                    float& cc = j ? cs1 : cs0;
                    float cn = sigf(fv) * cc + sigf(iv) * tanhf(gv);
                    cc = cn;
                    _Float16 hn = (_Float16)(sigf(ov) * tanhf(cn));
                    pv |= (unsigned)__builtin_bit_cast(unsigned short, hn) << (16 * j);
                }
                stcc(h0r + (size_t)(s & 7) * RSLOT + (size_t)(grow + srow) * Hx + u0 + 2 * sc, pv);
            }
            vm0();
            __syncthreads();
            if (tid == 0)
                __hip_atomic_fetch_add(c0p, 1u, __ATOMIC_RELAXED, __HIP_MEMORY_SCOPE_AGENT);
        }
    } else {
        // -------- layer 1 --------
        half8 W1a[16], W1b[16], W2a[16], W2b[16];
        const int wrA = wv * Hx + u0 + n, wrB = wrA + 16;
        #pragma unroll
        for (int c = 0; c < 16; ++c) {
            W1a[c] = cvt8(w_ih_l1 + (size_t)wrA * Hx + c * 32 + koff);
            W1b[c] = cvt8(w_ih_l1 + (size_t)wrB * Hx + c * 32 + koff);
            W2a[c] = cvt8(w_hh_l1 + (size_t)wrA * Hx + c * 32 + koff);
            W2b[c] = cvt8(w_hh_l1 + (size_t)wrB * Hx + c * 32 + koff);
        }

        for (int s = 0; s < Tt; ++s) {
            if (tid == 0) {
                unsigned t0 = 16u * (unsigned)(s + 1);
                unsigned t1 = s ? 16u * (unsigned)s : 0u;
                unsigned a = ldctr(c0p);
                unsigned b = s ? ldctr(c1p) : 0u;
                while (a < t0 || b < t1) {
                    __builtin_amdgcn_s_sleep(1);
                    a = ldctr(c0p);
                    if (s) b = ldctr(c1p);
                }
            }
            __syncthreads();
            // stage h0[s] (+ h1[s-1]) via MALL-coherent loads
            const _Float16* hp0 = h0r + (size_t)(s & 7) * RSLOT
                                + (size_t)(grow + srow) * Hx + sc * 32;
            half8 v0 = ldcc(hp0), v1 = ldcc(hp0 + 8), v2 = ldcc(hp0 + 16), v3 = ldcc(hp0 + 24);
            half8 w0, w1, w2, w3;
            if (s > 0) {
                const _Float16* hp1 = h1r + (size_t)((s - 1) & 7) * RSLOT
                                    + (size_t)(grow + srow) * Hx + sc * 32;
                w0 = ldcc(hp1); w1 = ldcc(hp1 + 8); w2 = ldcc(hp1 + 16); w3 = ldcc(hp1 + 24);
            }
            vm0();
            *(half8*)(bufX + srow * LSTR + sc * 32)      = v0;
            *(half8*)(bufX + srow * LSTR + sc * 32 + 8)  = v1;
            *(half8*)(bufX + srow * LSTR + sc * 32 + 16) = v2;
            *(half8*)(bufX + srow * LSTR + sc * 32 + 24) = v3;
            if (s > 0) {
                *(half8*)(bufH + srow * LSTR + sc * 32)      = w0;
                *(half8*)(bufH + srow * LSTR + sc * 32 + 8)  = w1;
                *(half8*)(bufH + srow * LSTR + sc * 32 + 16) = w2;
                *(half8*)(bufH + srow * LSTR + sc * 32 + 24) = w3;
            }
            __syncthreads();
            float4v a0 = {0.f,0.f,0.f,0.f}, a1 = {0.f,0.f,0.f,0.f};
            mfma2<16>(bufX, arow, koff, W1a, W1b, a0, a1);
            if (s > 0)
                mfma2<16>(bufH, arow, koff, W2a, W2b, a0, a1);
            #pragma unroll
            for (int r = 0; r < 4; ++r) {
                gbuf[wv][quad * 4 + r][n]      = a0[r];
                gbuf[wv][quad * 4 + r][16 + n] = a1[r];
            }
            __syncthreads();
            {
                unsigned pv = 0;
                #pragma unroll
                for (int j = 0; j < 2; ++j) {
                    float iv = gbuf[0][srow][2 * sc + j] + bias[0][j];
                    float fv = gbuf[1][srow][2 * sc + j] + bias[1][j];
                    float gv = gbuf[2][srow][2 * sc + j] + bias[2][j];
                    float ov = gbuf[3][srow][2 * sc + j] + bias[3][j];
                    float& cc = j ? cs1 : cs0;
                    float cn = sigf(fv) * cc + sigf(iv) * tanhf(gv);
                    cc = cn;
                    _Float16 hn = (_Float16)(sigf(ov) * tanhf(cn));
                    pv |= (unsigned)__builtin_bit_cast(unsigned short, hn) << (16 * j);
                }
                stcc(h1r + (size_t)(s & 7) * RSLOT + (size_t)(grow + srow) * Hx + u0 + 2 * sc, pv);
            }
            vm0();
            __syncthreads();
            if (tid == 0)
                __hip_atomic_fetch_add(c1p, 1u, __ATOMIC_RELAXED, __HIP_MEMORY_SCOPE_AGENT);
        }
    }
}

// FC head; h read MALL-coherently (it was written with sc0sc1 stores).
__global__ __launch_bounds__(64) void fc_kernel(
    const _Float16* __restrict__ h1,
    const float* __restrict__ fc_w, const float* __restrict__ fc_b,
    const float* __restrict__ fc2_w, const float* __restrict__ fc2_b,
    float* __restrict__ out)
{
    const int b = blockIdx.x;
    const int j = threadIdx.x;
    const _Float16* h = h1 + (size_t)b * Hx;
    const float* w = fc_w + (size_t)j * Hx;
    float acc = fc_b[j];
    for (int k = 0; k < Hx; k += 2) {
        unsigned pv = __hip_atomic_load((const unsigned*)(h + k),
                                        __ATOMIC_RELAXED, __HIP_MEMORY_SCOPE_AGENT);
        _Float16 lo = __builtin_bit_cast(_Float16, (unsigned short)(pv & 0xffffu));
        _Float16 hi = __builtin_bit_cast(_Float16, (unsigned short)(pv >> 16));
        acc += (float)lo * w[k] + (float)hi * w[k + 1];
    }
    float p = fmaxf(acc, 0.0f) * fc2_w[j];
    #pragma unroll
    for (int off = 32; off; off >>= 1) p += __shfl_down(p, off);
    if (j == 0) out[b] = 1.0f / (1.0f + expf(-(p + fc2_b[0])));
}

extern "C" void kernel_launch(void* const* d_in, const int* in_sizes, int n_in,
                              void* d_out, int out_size, void* d_ws, size_t ws_size,
                              hipStream_t stream) {
    const float* x       = (const float*)d_in[0];
    // d_in[1] = length_list : unused by the reference output
    const float* w_ih_l0 = (const float*)d_in[2];
    const float* w_hh_l0 = (const float*)d_in[3];
    const float* b_ih_l0 = (const float*)d_in[4];
    const float* b_hh_l0 = (const float*)d_in[5];
    const float* w_ih_l1 = (const float*)d_in[6];
    const float* w_hh_l1 = (const float*)d_in[7];
    const float* b_ih_l1 = (const float*)d_in[8];
    const float* b_hh_l1 = (const float*)d_in[9];
    const float* fc_w    = (const float*)d_in[10];
    const float* fc_b    = (const float*)d_in[11];
    const float* fc2_w   = (const float*)d_in[12];
    const float* fc2_b   = (const float*)d_in[13];
    float* out = (float*)d_out;

    // ws: [0,2KB) counters | [4KB, +1MB) h0 ring | [+1MB, +1MB) h1 ring
    char* ws = (char*)d_ws;
    unsigned* ctr = (unsigned*)ws;
    _Float16* h0r = (_Float16*)(ws + 4096);
    _Float16* h1r = (_Float16*)(ws + 4096 + RING * RSLOT * sizeof(_Float16));

    zero_ctr<<<1, 512, 0, stream>>>(ctr);
    lstm_persist<<<256, 256, 0, stream>>>(x,
        w_ih_l0, w_hh_l0, b_ih_l0, b_hh_l0,
        w_ih_l1, w_hh_l1, b_ih_l1, b_hh_l1,
        ctr, h0r, h1r);
    // final h1 is at ring slot (1023 & 7) = 7
    fc_kernel<<<Bx, 64, 0, stream>>>(h1r + 7 * RSLOT, fc_w, fc_b, fc2_w, fc2_b, out);
}